// Round 7
// baseline (331.386 us; speedup 1.0000x reference)
//
#include <hip/hip_runtime.h>
#include <hip/hip_fp16.h>

#define CAP 128   // max edges (per node-pair) handled by the fast LDS path

__device__ __forceinline__ float sel4(float4 v, int h) {
  return h == 0 ? v.x : h == 1 ? v.y : h == 2 ? v.z : v.w;
}

// ---------------- tiled GEMM + attention logits ----------------
// Per block: stage X tile [64 rows x K] + W [K x 64] in LDS (all loads
// lane-coalesced float4). Each wave computes 16 rows x 64 cols. hp written
// fp16 (halves node_agg's gather traffic). Optionally applies per-column BN
// (coeffs computed inline from bnsum/bnsq) + ReLU while staging X.
template<int K, bool APPLY_BN>
__global__ void __launch_bounds__(256, 4)
gemm_tiled(const float* __restrict__ X, const float* __restrict__ W,
           const float* __restrict__ a_s, const float* __restrict__ a_d,
           const float* __restrict__ bnsum, const float* __restrict__ bnsq,
           const float* __restrict__ g, const float* __restrict__ be,
           __half* __restrict__ hp, float* __restrict__ al_s,
           float* __restrict__ al_d, int n)
{
  __shared__ float Wl[(K / 4) * 64 * 4];  // [(k4*64+lane)*4+c] = W[(k4*4+c)*64+lane]
  __shared__ float Xt[64 * K];            // row-major [64][K]

  for (int gi = threadIdx.x; gi < (K / 4) * 64; gi += 256) {
    int k4 = gi >> 6, ln = gi & 63;
    float4 w;
    w.x = W[(k4 * 4 + 0) * 64 + ln];
    w.y = W[(k4 * 4 + 1) * 64 + ln];
    w.z = W[(k4 * 4 + 2) * 64 + ln];
    w.w = W[(k4 * 4 + 3) * 64 + ln];
    *(float4*)&Wl[gi * 4] = w;
  }

  int row0 = blockIdx.x * 64;
  int nrows = min(64, n - row0);
  float4 sc, sh;
  if (APPLY_BN) {   // K==64 path: float4 col group fixed per thread
    int cg = (threadIdx.x & 15) * 4;
    float inv_n = 1.f / (float)n;
#pragma unroll
    for (int q = 0; q < 4; ++q) {
      float mu  = bnsum[cg + q] * inv_n;
      float var = bnsq[cg + q] * inv_n - mu * mu;
      float s   = g[cg + q] * rsqrtf(var + 1e-5f);
      ((float*)&sc)[q] = s;
      ((float*)&sh)[q] = be[cg + q] - mu * s;
    }
  }
  const float4* src = (const float4*)(X + (size_t)row0 * K);
  int nf4 = nrows * (K / 4);
  for (int i = threadIdx.x; i < nf4; i += 256) {
    float4 v = src[i];
    if (APPLY_BN) {
      v.x = fmaxf(v.x * sc.x + sh.x, 0.f);
      v.y = fmaxf(v.y * sc.y + sh.y, 0.f);
      v.z = fmaxf(v.z * sc.z + sh.z, 0.f);
      v.w = fmaxf(v.w * sc.w + sh.w, 0.f);
    }
    *(float4*)&Xt[i * 4] = v;
  }
  __syncthreads();

  int lane = threadIdx.x & 63;
  int wid  = threadIdx.x >> 6;
  int rbase = wid * 16;
  float acc[16];
#pragma unroll
  for (int r = 0; r < 16; ++r) acc[r] = 0.f;

  for (int k4 = 0; k4 < K / 4; ++k4) {
    float4 wv = *(const float4*)&Wl[(k4 * 64 + lane) * 4];
#pragma unroll
    for (int r = 0; r < 16; ++r) {
      float4 xv = *(const float4*)&Xt[(rbase + r) * K + k4 * 4];
      acc[r] += xv.x * wv.x + xv.y * wv.y + xv.z * wv.z + xv.w * wv.w;
    }
  }

  float as_l = a_s[lane], ad_l = a_d[lane];
  int h = lane >> 4, c = lane & 15;
#pragma unroll
  for (int r = 0; r < 16; ++r) {
    int lr = rbase + r;
    if (lr >= nrows) break;
    int row = row0 + lr;
    float a = acc[r];
    hp[(size_t)row * 64 + lane] = __float2half(a);
    float vs = a * as_l;
    float vd = a * ad_l;
#pragma unroll
    for (int off = 8; off >= 1; off >>= 1) {
      vs += __shfl_xor(vs, off, 64);
      vd += __shfl_xor(vd, off, 64);
    }
    if (c == 0) { al_s[row * 4 + h] = vs; al_d[row * 4 + h] = vd; }
  }
}

// ---------------- CSR build (once per call; reused by both layers) ----------------
__global__ void hist_k(const int* __restrict__ ei, int E, int N, int* __restrict__ count)
{
  int e = blockIdx.x * 256 + threadIdx.x;
  int Et = E + N;
  if (e >= Et) return;
  int d = (e < E) ? ei[E + e] : (e - E);
  atomicAdd(&count[d], 1);
}

__global__ void scan_block_k(const int* __restrict__ count, int* __restrict__ row_ptr,
                             int* __restrict__ partial, int n)
{
  __shared__ int woff[16];
  int tid = threadIdx.x;
  int i = blockIdx.x * 1024 + tid;
  int v = (i < n) ? count[i] : 0;
  int lane = tid & 63, wid = tid >> 6;
  int incl = v;
#pragma unroll
  for (int off = 1; off < 64; off <<= 1) {
    int t = __shfl_up(incl, off, 64);
    if (lane >= off) incl += t;
  }
  if (lane == 63) woff[wid] = incl;
  __syncthreads();
  if (tid < 16) {
    int wv = woff[tid];
    int winc = wv;
#pragma unroll
    for (int off = 1; off < 16; off <<= 1) {
      int t = __shfl_up(winc, off, 64);
      if (tid >= off) winc += t;
    }
    woff[tid] = winc - wv;
    if (tid == 15) partial[blockIdx.x] = winc;
  }
  __syncthreads();
  if (i < n) row_ptr[i] = woff[wid] + incl - v;
}

__global__ void scan_partial_k(int* __restrict__ partial, int* __restrict__ row_ptr,
                               int nb, int n)
{
  int tid = threadIdx.x;  // 64 threads
  int v = (tid < nb) ? partial[tid] : 0;
  int incl = v;
#pragma unroll
  for (int off = 1; off < 64; off <<= 1) {
    int t = __shfl_up(incl, off, 64);
    if (tid >= off) incl += t;
  }
  if (tid < nb) partial[tid] = incl - v;
  if (tid == 63) row_ptr[n] = incl;
}

__global__ void scan_add_k(int* __restrict__ row_ptr, int* __restrict__ cursor,
                           const int* __restrict__ partial, int n)
{
  int i = blockIdx.x * 1024 + threadIdx.x;
  if (i < n) {
    int r = row_ptr[i] + partial[blockIdx.x];
    row_ptr[i] = r;
    cursor[i] = r;
  }
}

__global__ void scatter_k(const int* __restrict__ ei, int E, int N,
                          int* __restrict__ cursor, int* __restrict__ col_src,
                          int* __restrict__ col_dst)
{
  int e = blockIdx.x * 256 + threadIdx.x;
  int Et = E + N;
  if (e >= Et) return;
  int s, d;
  if (e < E) { s = ei[e]; d = ei[E + e]; } else { s = d = e - E; }
  int pos = atomicAdd(&cursor[d], 1);
  col_src[pos] = s;
  col_dst[pos] = d;
}

// ---------------- edge-parallel softmax weights ----------------
// w[e][h] = exp(leaky_relu(al_s[src]+al_d[dst])). Fully parallel streaming;
// al_s/al_d tables are L2-resident (800 KB each). No max subtraction needed:
// softmax is shift-invariant and |logit| is small enough for fp32 exp.
__global__ void eweight_k(const int* __restrict__ csrc, const int* __restrict__ cdst,
                          const float* __restrict__ al_s, const float* __restrict__ al_d,
                          float4* __restrict__ ew, int Et)
{
  int e = blockIdx.x * 256 + threadIdx.x;
  if (e >= Et) return;
  int s = csrc[e], d = cdst[e];
  float4 a = *(const float4*)(al_s + (size_t)s * 4);
  float4 b = *(const float4*)(al_d + (size_t)d * 4);
  float ex = a.x + b.x; ex = ex >= 0.f ? ex : 0.2f * ex;
  float ey = a.y + b.y; ey = ey >= 0.f ? ey : 0.2f * ey;
  float ez = a.z + b.z; ez = ez >= 0.f ? ez : 0.2f * ez;
  float ewv = a.w + b.w; ewv = ewv >= 0.f ? ewv : 0.2f * ewv;
  ew[e] = make_float4(__expf(ex), __expf(ey), __expf(ez), __expf(ewv));
}

// ---------------- per-node aggregation (paired nodes, precomputed weights) -------
// Each wave handles TWO adjacent dst nodes per iteration. Stage: one 64-lane
// pass loads the pair's col_src + ew (coalesced) into LDS and builds 8 masked
// per-head partial sums -> one 6-step shuffle reduce gives both denominators.
// Pass B: flat 8-deep loop over the pair's combined edges; masked dual
// accumulation (cndmask'ed weight) keeps independent loads streaming.
__global__ void __launch_bounds__(256)
node_agg(const int* __restrict__ row_ptr, const int* __restrict__ col_src,
         const float4* __restrict__ ew, const __half* __restrict__ hp,
         const float* __restrict__ bias, float* __restrict__ hpre,
         float* __restrict__ bnsum, float* __restrict__ bnsq, int n)
{
  __shared__ int   sh_s[4][CAP];
  __shared__ float sh_w[4][CAP * 4];
  __shared__ float shs[64], shq[64];

  int lane = threadIdx.x & 63;
  int wid  = threadIdx.x >> 6;
  int h    = lane >> 4;
  float b  = bias[lane];
  float lsum = 0.f, lsq = 0.f;
  int nwaves = gridDim.x * 4;
  int npairs = (n + 1) >> 1;

  for (int p = blockIdx.x * 4 + wid; p < npairs; p += nwaves) {
    int d = p * 2;
    bool has1 = (d + 1) < n;
    int beg0 = row_ptr[d];
    int end0 = row_ptr[d + 1];
    int end1 = has1 ? row_ptr[d + 2] : end0;
    int deg0 = end0 - beg0;
    int degP = end1 - beg0;
    float o0, o1 = 0.f;

    if (degP <= CAP) {
      float p00 = 0.f, p01 = 0.f, p02 = 0.f, p03 = 0.f;
      float p10 = 0.f, p11 = 0.f, p12 = 0.f, p13 = 0.f;
      for (int jb = 0; jb < degP; jb += 64) {
        int jj = jb + lane;
        if (jj < degP) {
          int s = col_src[beg0 + jj];
          float4 w = ew[beg0 + jj];
          sh_s[wid][jj] = s;
          *(float4*)&sh_w[wid][jj * 4] = w;
          if (jj < deg0) { p00 += w.x; p01 += w.y; p02 += w.z; p03 += w.w; }
          else           { p10 += w.x; p11 += w.y; p12 += w.z; p13 += w.w; }
        }
      }
#pragma unroll
      for (int off = 32; off >= 1; off >>= 1) {
        p00 += __shfl_xor(p00, off, 64); p01 += __shfl_xor(p01, off, 64);
        p02 += __shfl_xor(p02, off, 64); p03 += __shfl_xor(p03, off, 64);
        p10 += __shfl_xor(p10, off, 64); p11 += __shfl_xor(p11, off, 64);
        p12 += __shfl_xor(p12, off, 64); p13 += __shfl_xor(p13, off, 64);
      }
      float den0 = (h == 0) ? p00 : (h == 1) ? p01 : (h == 2) ? p02 : p03;
      float den1 = (h == 0) ? p10 : (h == 1) ? p11 : (h == 2) ? p12 : p13;

      float acc0 = 0.f, acc1 = 0.f;
      int j = 0;
      for (; j + 8 <= degP; j += 8) {
#pragma unroll
        for (int k = 0; k < 8; ++k) {
          int jk = j + k;
          int s = sh_s[wid][jk];
          float wh = sh_w[wid][jk * 4 + h];
          float v = __half2float(hp[(size_t)s * 64 + lane]);
          float w0 = (jk < deg0) ? wh : 0.f;
          acc0 += w0 * v;
          acc1 += (wh - w0) * v;
        }
      }
      for (; j < degP; ++j) {
        int s = sh_s[wid][j];
        float wh = sh_w[wid][j * 4 + h];
        float v = __half2float(hp[(size_t)s * 64 + lane]);
        float w0 = (j < deg0) ? wh : 0.f;
        acc0 += w0 * v;
        acc1 += (wh - w0) * v;
      }
      o0 = acc0 / (den0 + 1e-16f) + b;
      if (has1) o1 = acc1 / (den1 + 1e-16f) + b;
    } else {
      // fallback: serial per node (degP > CAP; essentially never for this graph)
      float den = 0.f, acc = 0.f;
      for (int j = beg0; j < end0; ++j) {
        float wh = sel4(ew[j], h);
        den += wh;
        acc += wh * __half2float(hp[(size_t)col_src[j] * 64 + lane]);
      }
      o0 = acc / (den + 1e-16f) + b;
      if (has1) {
        den = 0.f; acc = 0.f;
        for (int j = end0; j < end1; ++j) {
          float wh = sel4(ew[j], h);
          den += wh;
          acc += wh * __half2float(hp[(size_t)col_src[j] * 64 + lane]);
        }
        o1 = acc / (den + 1e-16f) + b;
      }
    }

    hpre[(size_t)d * 64 + lane] = o0;
    lsum += o0; lsq += o0 * o0;
    if (has1) {
      hpre[(size_t)(d + 1) * 64 + lane] = o1;
      lsum += o1; lsq += o1 * o1;
    }
  }

  if (threadIdx.x < 64) { shs[threadIdx.x] = 0.f; shq[threadIdx.x] = 0.f; }
  __syncthreads();
  atomicAdd(&shs[lane], lsum);
  atomicAdd(&shq[lane], lsq);
  __syncthreads();
  if (threadIdx.x < 64) {
    atomicAdd(&bnsum[threadIdx.x], shs[threadIdx.x]);
    atomicAdd(&bnsq[threadIdx.x],  shq[threadIdx.x]);
  }
}

// ---------------- BatchNorm apply (final layer, in-place on out) ----------------
__global__ void bn_apply(float* __restrict__ buf, const float* __restrict__ bnsum,
                         const float* __restrict__ bnsq, const float* __restrict__ g,
                         const float* __restrict__ be, int n)
{
  size_t i = (size_t)blockIdx.x * 256 + threadIdx.x;
  size_t total = (size_t)n * 64;
  if (i >= total) return;
  int c = (int)(i & 63);
  float inv_n = 1.f / (float)n;
  float mu  = bnsum[c] * inv_n;
  float var = bnsq[c] * inv_n - mu * mu;    // biased var, matches jnp .var()
  buf[i] = (buf[i] - mu) * rsqrtf(var + 1e-5f) * g[c] + be[c];
}

extern "C" void kernel_launch(void* const* d_in, const int* in_sizes, int n_in,
                              void* d_out, int out_size, void* d_ws, size_t ws_size,
                              hipStream_t stream) {
  const float* x   = (const float*)d_in[0];
  const int*   ei  = (const int*)d_in[1];
  const float* W0  = (const float*)d_in[2];
  const float* as0 = (const float*)d_in[3];
  const float* ad0 = (const float*)d_in[4];
  const float* b0  = (const float*)d_in[5];
  const float* g0  = (const float*)d_in[6];
  const float* be0 = (const float*)d_in[7];
  const float* W1  = (const float*)d_in[8];
  const float* as1 = (const float*)d_in[9];
  const float* ad1 = (const float*)d_in[10];
  const float* b1  = (const float*)d_in[11];
  const float* g1  = (const float*)d_in[12];
  const float* be1 = (const float*)d_in[13];
  float* out = (float*)d_out;

  int N = in_sizes[0] / 128;
  int E = in_sizes[1] / 2;
  int Et = E + N;

  char* w = (char*)d_ws;
  auto alloc = [&](size_t bytes) {
    char* p = w; w += (bytes + 255) & ~255ull; return p;
  };
  // count + bn stats contiguous -> single memset clears all of them
  int*    count = (int*)alloc((size_t)N * 4 + 4 * 64 * 4);
  float*  bnsum0 = (float*)(count + N);
  float*  bnsq0  = bnsum0 + 64;
  float*  bnsum1 = bnsq0 + 64;
  float*  bnsq1  = bnsum1 + 64;
  __half* hp    = (__half*)alloc((size_t)N * 64 * 2);   // fp16 hp (gathered matrix)
  float*  hpre0 = (float*)alloc((size_t)N * 64 * 4);    // layer-0 pre-BN output
  float*  als   = (float*)alloc((size_t)N * 4 * 4);
  float*  ald   = (float*)alloc((size_t)N * 4 * 4);
  int*    rowp  = (int*)alloc((size_t)(N + 1) * 4);
  int*    cursor= (int*)alloc((size_t)N * 4);
  int*    parts = (int*)alloc(64 * 4);
  int*    csrc  = (int*)alloc((size_t)Et * 4);
  int*    cdst  = (int*)alloc((size_t)Et * 4);
  float4* ew    = (float4*)alloc((size_t)Et * 16);

  dim3 blk(256);
  int gEt   = (Et + 255) / 256;
  int gN64  = (N * 64 + 255) / 256;
  int nb    = (N + 1023) / 1024;
  int gTile = (N + 63) / 64;

  hipMemsetAsync(count, 0, (size_t)N * 4 + 4 * 64 * 4, stream);

  // ---- CSR build (shared by both layers) ----
  hist_k<<<gEt, blk, 0, stream>>>(ei, E, N, count);
  scan_block_k<<<nb, 1024, 0, stream>>>(count, rowp, parts, N);
  scan_partial_k<<<1, 64, 0, stream>>>(parts, rowp, nb, N);
  scan_add_k<<<nb, 1024, 0, stream>>>(rowp, cursor, parts, N);
  scatter_k<<<gEt, blk, 0, stream>>>(ei, E, N, cursor, csrc, cdst);

  // ---- layer 0 ----
  gemm_tiled<128, false><<<gTile, blk, 0, stream>>>(x, W0, as0, ad0,
                                                    nullptr, nullptr, nullptr, nullptr,
                                                    hp, als, ald, N);
  eweight_k<<<gEt, blk, 0, stream>>>(csrc, cdst, als, ald, ew, Et);
  node_agg<<<2048, blk, 0, stream>>>(rowp, csrc, ew, hp, b0,
                                     hpre0, bnsum0, bnsq0, N);

  // ---- layer 1 (BN0 coeffs computed inline + ReLU fused into X staging) ----
  gemm_tiled<64, true><<<gTile, blk, 0, stream>>>(hpre0, W1, as1, ad1,
                                                  bnsum0, bnsq0, g0, be0,
                                                  hp, als, ald, N);
  eweight_k<<<gEt, blk, 0, stream>>>(csrc, cdst, als, ald, ew, Et);
  node_agg<<<2048, blk, 0, stream>>>(rowp, csrc, ew, hp, b1,
                                     out, bnsum1, bnsq1, N);
  bn_apply<<<gN64, blk, 0, stream>>>(out, bnsum1, bnsq1, g1, be1, N);
}